// Round 5
// baseline (971.015 us; speedup 1.0000x reference)
//
#include <hip/hip_runtime.h>
#include <hip/hip_bf16.h>
#include <stdint.h>

// LFreqEmbed — ROUND 5: round-3 MFMA kernel with FLOAT32 output epilogue.
// Diagnosis from rounds 2/3/4 (bit-identical absmax across MFMA and pure-VALU
// kernels): gather + MFMA compute are provably correct; the shared bug was
// writing bf16 into what is actually a float32 output buffer.
//   out[b,l,e] = sum_d g[b,l,d] * W[e,d] + bias[e]   (f32 out)
//   g[b,l, c*448 + kk] = x[b, c, a_idx[l,kk], b_idx[l,kk]]
// M = 256*112 = 28672, N = 768, K = 1344. bf16 inputs (probed), fp32 accum/out.

#define IMG   224
#define NLEV  112
#define CIN   3
#define DIN   1344
#define EMB   768
#define MTOT  28672
#define BM    128
#define BN    128
#define BK    64
#define LDP   72   // padded leading dim: stride 144B -> 2-way LDS aliasing (free, m136)

typedef __attribute__((ext_vector_type(8))) short   short8;
typedef __attribute__((ext_vector_type(4))) float   floatx4;

__device__ __forceinline__ unsigned short f2bf(float f) {
    unsigned u = __float_as_uint(f);
    unsigned r = (u + 0x7fffu + ((u >> 16) & 1u)) >> 16;
    return (unsigned short)r;
}
__device__ __forceinline__ float bf2f(unsigned short s) {
    return __uint_as_float(((unsigned)s) << 16);
}
__device__ __forceinline__ unsigned pack2(float a, float b) {
    return (unsigned)f2bf(a) | ((unsigned)f2bf(b) << 16);
}

// dtype probe: bf16 inputs -> W[2k] are real weights (|W|<0.2 -> u16<0x4000).
// f32 inputs -> W[2k] are mantissa halves (uniform bits) -> flag=1 w.p. 1-2^-4096.
__global__ void detect_dtype(const unsigned short* __restrict__ W, int* flag) {
    __shared__ int s;
    if (threadIdx.x == 0) s = 0;
    __syncthreads();
    int bad = 0;
    for (int k = threadIdx.x; k < 4096; k += 256) {
        unsigned v = (unsigned)W[2 * k] & 0x7FFFu;
        if (v >= 0x4000u) bad = 1;
    }
    if (bad) atomicOr(&s, 1);
    __syncthreads();
    if (threadIdx.x == 0) *flag = s;   // 0 = bf16 inputs, 1 = f32 inputs
}

template<bool F32>
__global__ __launch_bounds__(256, 2)
void lfreq_fused_gemm(const void* __restrict__ Xv,
                      const void* __restrict__ Wv,
                      const void* __restrict__ Bv,
                      const int* __restrict__ Aidx,
                      const int* __restrict__ Bidx,
                      float* __restrict__ Out,
                      const int* __restrict__ flag)
{
    if (*flag != (F32 ? 1 : 0)) return;   // uniform across block

    __shared__ __align__(16) unsigned short As[BM][LDP];
    __shared__ __align__(16) unsigned short Bs[BN][LDP];

    const int tid   = threadIdx.x;
    const int wave  = tid >> 6;
    const int lane  = tid & 63;
    const int mBase = blockIdx.x * BM;
    const int nBase = blockIdx.y * BN;

    // ---- staging map: row = tid>>1, half = tid&1 -> 32 elems each ----
    const int srow  = tid >> 1;
    const int shalf = tid & 1;
    const int am = mBase + srow;
    const int bb = am / NLEV;
    const int ll = am - bb * NLEV;

    floatx4 acc[4][4];
    #pragma unroll
    for (int i = 0; i < 4; i++)
        #pragma unroll
        for (int jj = 0; jj < 4; jj++)
            acc[i][jj] = (floatx4){0.f, 0.f, 0.f, 0.f};

    const int wm   = wave >> 1;          // wave tile: 64x64 at (wm*64, wn*64)
    const int wn   = wave & 1;
    const int lrow = lane & 15;
    const int kq   = (lane >> 4) << 3;   // 0,8,16,24

    for (int kt = 0; kt < DIN; kt += BK) {
        // ---- stage W tile: Bs[row][k] = W[nBase+row][kt+k] ----
        {
            const int koff = kt + shalf * 32;
            uint4* dst = (uint4*)&Bs[srow][shalf * 32];
            if (F32) {
                const float4* g = (const float4*)((const float*)Wv
                                + (size_t)(nBase + srow) * DIN + koff);
                #pragma unroll
                for (int q = 0; q < 4; q++) {
                    float4 v0 = g[2*q], v1 = g[2*q+1];
                    uint4 o;
                    o.x = pack2(v0.x, v0.y); o.y = pack2(v0.z, v0.w);
                    o.z = pack2(v1.x, v1.y); o.w = pack2(v1.z, v1.w);
                    dst[q] = o;
                }
            } else {
                const uint4* g = (const uint4*)((const unsigned short*)Wv
                               + (size_t)(nBase + srow) * DIN + koff);
                #pragma unroll
                for (int q = 0; q < 4; q++) dst[q] = g[q];
            }
        }
        // ---- stage A tile via real index arrays ----
        {
            const int d0  = kt + shalf * 32;   // 32-aligned; 448=14*32 -> one channel
            const int c   = (d0 >= 896) ? 2 : (d0 >= 448 ? 1 : 0);
            const int kk0 = d0 - c * 448;
            const int4* ap = (const int4*)(Aidx + ll * 448 + kk0);
            const int4* bp = (const int4*)(Bidx + ll * 448 + kk0);
            unsigned* du = (unsigned*)&As[srow][shalf * 32];
            if (F32) {
                const float* plane = (const float*)Xv
                    + (size_t)bb * (CIN * IMG * IMG) + (size_t)c * (IMG * IMG);
                #pragma unroll
                for (int q = 0; q < 8; q++) {
                    int4 av = ap[q], bv = bp[q];
                    du[2*q+0] = pack2(plane[av.x * IMG + bv.x], plane[av.y * IMG + bv.y]);
                    du[2*q+1] = pack2(plane[av.z * IMG + bv.z], plane[av.w * IMG + bv.w]);
                }
            } else {
                const unsigned short* plane = (const unsigned short*)Xv
                    + (size_t)bb * (CIN * IMG * IMG) + (size_t)c * (IMG * IMG);
                #pragma unroll
                for (int q = 0; q < 8; q++) {
                    int4 av = ap[q], bv = bp[q];
                    unsigned e0 = plane[av.x * IMG + bv.x];
                    unsigned e1 = plane[av.y * IMG + bv.y];
                    unsigned e2 = plane[av.z * IMG + bv.z];
                    unsigned e3 = plane[av.w * IMG + bv.w];
                    du[2*q+0] = e0 | (e1 << 16);
                    du[2*q+1] = e2 | (e3 << 16);
                }
            }
        }
        __syncthreads();

        // ---- MFMA on staged tiles (A.B^T idiom, identical fragment reads) ----
        #pragma unroll
        for (int k0 = 0; k0 < BK; k0 += 32) {
            short8 af[4], bf[4];
            #pragma unroll
            for (int mi = 0; mi < 4; mi++)
                af[mi] = *(const short8*)&As[wm*64 + mi*16 + lrow][k0 + kq];
            #pragma unroll
            for (int ni = 0; ni < 4; ni++)
                bf[ni] = *(const short8*)&Bs[wn*64 + ni*16 + lrow][k0 + kq];
            #pragma unroll
            for (int mi = 0; mi < 4; mi++)
                #pragma unroll
                for (int ni = 0; ni < 4; ni++)
                    acc[mi][ni] = __builtin_amdgcn_mfma_f32_16x16x32_bf16(
                        af[mi], bf[ni], acc[mi][ni], 0, 0, 0);
        }
        __syncthreads();
    }

    // ---- epilogue: FLOAT32 output. C/D layout col=lane&15, row=(lane>>4)*4+reg ----
    const int quad = lane >> 4;
    #pragma unroll
    for (int ni = 0; ni < 4; ni++) {
        const int col = nBase + wn*64 + ni*16 + lrow;
        const float bv = F32 ? ((const float*)Bv)[col]
                             : bf2f(((const unsigned short*)Bv)[col]);
        #pragma unroll
        for (int mi = 0; mi < 4; mi++) {
            const int rbase = mBase + wm*64 + mi*16 + quad*4;
            floatx4 a = acc[mi][ni];
            Out[(size_t)(rbase+0)*EMB + col] = a[0] + bv;
            Out[(size_t)(rbase+1)*EMB + col] = a[1] + bv;
            Out[(size_t)(rbase+2)*EMB + col] = a[2] + bv;
            Out[(size_t)(rbase+3)*EMB + col] = a[3] + bv;
        }
    }
}

extern "C" void kernel_launch(void* const* d_in, const int* in_sizes, int n_in,
                              void* d_out, int out_size, void* d_ws, size_t ws_size,
                              hipStream_t stream) {
    const void* X    = d_in[0];              // x: [256,3,224,224] bf16 (probed)
    const void* Wt   = d_in[1];              // W: [768,1344]
    const void* Bias = d_in[2];              // b: [768]
    const int*  Ai   = (const int*)d_in[3];  // a_idx: [112,448] int32
    const int*  Bi   = (const int*)d_in[4];  // b_idx: [112,448] int32
    float* Out = (float*)d_out;              // f32 [256,112,768]
    int* flag = (int*)d_ws;

    detect_dtype<<<dim3(1), dim3(256), 0, stream>>>((const unsigned short*)Wt, flag);

    dim3 grid(MTOT / BM, EMB / BN);   // 224 x 6
    dim3 block(256);
    lfreq_fused_gemm<false><<<grid, block, 0, stream>>>(X, Wt, Bias, Ai, Bi, Out, flag);
    lfreq_fused_gemm<true ><<<grid, block, 0, stream>>>(X, Wt, Bias, Ai, Bi, Out, flag);
}